// Round 8
// baseline (167.934 us; speedup 1.0000x reference)
//
#include <hip/hip_runtime.h>

#define NN 50000
#define NE 100000
#define IN_F 63
#define HID 64
#define NREL 8
#define RT 32                               // receivers per tile
#define NTILES ((NN + RT - 1) / RT)         // 1563
#define SCAN_BLKS ((NN + 255) / 256)        // 196

// ---- CSR build stage 1: receiver counts + sender degrees ------------------
__global__ __launch_bounds__(256) void count_kernel(const int* __restrict__ senders,
                                                    const int* __restrict__ receivers,
                                                    int* __restrict__ cnt,
                                                    int* __restrict__ scnt) {
    int e = blockIdx.x * 256 + threadIdx.x;
    if (e < NE) {
        atomicAdd(&cnt[receivers[e]], 1);
        atomicAdd(&scnt[senders[e]], 1);
    }
}

// ---- CSR build stage 2a: per-256-block exclusive scan ---------------------
__global__ __launch_bounds__(256) void scan1_kernel(const int* __restrict__ cnt,
                                                    int* __restrict__ offs,
                                                    int* __restrict__ bsum) {
    int i = blockIdx.x * 256 + threadIdx.x;
    int c = (i < NN) ? cnt[i] : 0;
    int lane = threadIdx.x & 63, wv = threadIdx.x >> 6;
    int x = c;
#pragma unroll
    for (int o = 1; o < 64; o <<= 1) {
        int y = __shfl_up(x, o, 64);
        if (lane >= o) x += y;
    }
    __shared__ int wtot[4];
    if (lane == 63) wtot[wv] = x;
    __syncthreads();
    int base = 0;
#pragma unroll
    for (int k = 0; k < 4; ++k) if (k < wv) base += wtot[k];
    int ex = base + x - c;
    if (i < NN) offs[i] = ex;
    if (threadIdx.x == 255) bsum[blockIdx.x] = ex + c;
}

// ---- CSR build stage 2b: scan the 196 block sums (one block) --------------
__global__ __launch_bounds__(256) void scan2_kernel(const int* __restrict__ bsum,
                                                    int* __restrict__ bbase) {
    int i = threadIdx.x;
    int c = (i < SCAN_BLKS) ? bsum[i] : 0;
    int lane = threadIdx.x & 63, wv = threadIdx.x >> 6;
    int x = c;
#pragma unroll
    for (int o = 1; o < 64; o <<= 1) {
        int y = __shfl_up(x, o, 64);
        if (lane >= o) x += y;
    }
    __shared__ int wtot[4];
    if (lane == 63) wtot[wv] = x;
    __syncthreads();
    int base = 0;
#pragma unroll
    for (int k = 0; k < 4; ++k) if (k < wv) base += wtot[k];
    bbase[i] = base + x - c;
}

// ---- CSR build stage 2c: add block bases; init cursor; offs[NN]=NE --------
__global__ __launch_bounds__(256) void scan3_kernel(int* __restrict__ offs,
                                                    const int* __restrict__ bbase,
                                                    int* __restrict__ cursor) {
    int i = blockIdx.x * 256 + threadIdx.x;
    if (i < NN) {
        int v = offs[i] + bbase[blockIdx.x];
        offs[i] = v;
        cursor[i] = v;
    }
    if (i == 0) offs[NN] = NE;
}

// ---- CSR build stage 3: scatter edges into receiver-sorted order ----------
// meta packs s (16b) | t (3b, <<16) | r&31 (5b, <<19); ns precomputed.
__global__ __launch_bounds__(256) void scatter_kernel(const int* __restrict__ senders,
                                                      const int* __restrict__ receivers,
                                                      const int* __restrict__ etypes,
                                                      const int* __restrict__ scnt,
                                                      int* __restrict__ cursor,
                                                      int* __restrict__ meta,
                                                      float* __restrict__ ns_srt) {
    int e = blockIdx.x * 256 + threadIdx.x;
    if (e < NE) {
        int r = receivers[e], s = senders[e], t = etypes[e];
        int pos = atomicAdd(&cursor[r], 1);
        meta[pos] = s | (t << 16) | ((r & (RT - 1)) << 19);
        ns_srt[pos] = rsqrtf(fmaxf((float)scnt[s], 1.0f));
    }
}

// ---- main: per-tile messages + LDS accumulate + fused readout -------------
// Block = 32-receiver tile (contiguous CSR edge range). 4 waves split the 8
// relations (2 passes each); kcol lives in VGPRs per (wave, relation) and is
// amortized over the tile's edges of that relation. Messages accumulate in
// an 8KB LDS tile via ds-atomics — ZERO global atomics, no agg array, no
// memset, and the relu/norm/root/w readout fuses here (kills readout1's
// 16MB round-trip). Round-4/6 evidence: 6.4M global atomic lane-ops were a
// ~43us floor; this removes all of them.
__global__ __launch_bounds__(256) void tile_kernel(const float* __restrict__ nodes,
                                                   const float* __restrict__ kernels,
                                                   const int* __restrict__ offs,
                                                   const int* __restrict__ meta,
                                                   const float* __restrict__ ns_srt,
                                                   const float* __restrict__ wvec,
                                                   float* __restrict__ partial) {
    __shared__ float acc[RT * HID];      // 8 KB
    __shared__ float wsum[4];
    const int lane = threadIdx.x & 63;
    const int wv = threadIdx.x >> 6;
    const int r0 = blockIdx.x * RT;
    const int nrows = min(RT, NN - r0);
    const int jbeg = offs[r0];
    const int jend = offs[r0 + nrows];

    for (int k = threadIdx.x; k < RT * HID; k += 256) acc[k] = 0.f;
    __syncthreads();

    for (int tp = 0; tp < 2; ++tp) {
        const int t = wv * 2 + tp;                       // this wave's relation
        float kcol[IN_F];
        const float* Kt = kernels + (size_t)t * IN_F * HID;
#pragma unroll
        for (int i = 0; i < IN_F; ++i) kcol[i] = Kt[i * HID + lane];

        for (int j = jbeg; j < jend; ++j) {
            const int mv = meta[j];                      // wave-uniform
            if (((mv >> 16) & 7) != t) continue;         // uniform branch
            const int s  = mv & 0xFFFF;
            const int rl = (mv >> 19) & 31;
            const float nsv = ns_srt[j];
            const float4* x4 = (const float4*)(nodes + (size_t)s * (IN_F + 1));
            float a0 = 0.f, a1 = 0.f, a2 = 0.f, a3 = 0.f;
#pragma unroll
            for (int jj = 0; jj < 16; ++jj) {
                const float4 v = x4[jj];
                a0 = fmaf(kcol[4 * jj + 0], v.x, a0);
                a1 = fmaf(kcol[4 * jj + 1], v.y, a1);
                a2 = fmaf(kcol[4 * jj + 2], v.z, a2);
                if (4 * jj + 3 < IN_F) a3 = fmaf(kcol[4 * jj + 3], v.w, a3);
            }
            atomicAdd(&acc[rl * HID + lane], ((a0 + a1) + (a2 + a3)) * nsv);
        }
    }
    __syncthreads();

    // fused readout: part_f = sum_rows relu(acc*nr)*root, then *w[f], reduce
    float part = 0.f;
    for (int k = 0; k < RT / 4; ++k) {
        const int row = wv * (RT / 4) + k;
        if (row >= nrows) break;
        const int r = r0 + row;
        const float dg = (float)(offs[r + 1] - offs[r]);
        const float nr_ = rsqrtf(fmaxf(dg, 1.0f));
        const float root = nodes[(size_t)r * (IN_F + 1) + IN_F];  // uniform
        part += fmaxf(acc[row * HID + lane] * nr_, 0.f) * root;
    }
    float v = part * wvec[lane];
#pragma unroll
    for (int o = 32; o > 0; o >>= 1) v += __shfl_xor(v, o, 64);
    if (lane == 0) wsum[wv] = v;
    __syncthreads();
    if (threadIdx.x == 0)
        partial[blockIdx.x] = (wsum[0] + wsum[1]) + (wsum[2] + wsum[3]);
}

// ---- final: sum tile partials + bias --------------------------------------
__global__ __launch_bounds__(256) void final_kernel(const float* __restrict__ partial,
                                                    const float* __restrict__ b,
                                                    float* __restrict__ out) {
    __shared__ float wsum[4];
    const int lane = threadIdx.x & 63;
    const int wv = threadIdx.x >> 6;
    float v = 0.f;
    for (int i = threadIdx.x; i < NTILES; i += 256) v += partial[i];
#pragma unroll
    for (int o = 32; o > 0; o >>= 1) v += __shfl_xor(v, o, 64);
    if (lane == 0) wsum[wv] = v;
    __syncthreads();
    if (threadIdx.x == 0)
        out[0] = (wsum[0] + wsum[1]) + (wsum[2] + wsum[3]) + b[0];
}

extern "C" void kernel_launch(void* const* d_in, const int* in_sizes, int n_in,
                              void* d_out, int out_size, void* d_ws, size_t ws_size,
                              hipStream_t stream) {
    const float* nodes     = (const float*)d_in[0];
    const int*   senders   = (const int*)d_in[1];
    const int*   receivers = (const int*)d_in[2];
    const int*   etypes    = (const int*)d_in[3];
    // d_in[4] = n_node (single graph; unused)
    const float* kernels   = (const float*)d_in[5];
    const float* dense_w   = (const float*)d_in[6];
    const float* dense_b   = (const float*)d_in[7];
    float* out = (float*)d_out;

    // workspace layout (all 4B elements)
    int*   cnt     = (int*)d_ws;                  // NN
    int*   scnt    = cnt + NN;                    // NN   (adjacent -> one memset)
    int*   offs    = scnt + NN;                   // NN+1
    int*   cursor  = offs + NN + 1;               // NN
    int*   bsum    = cursor + NN;                 // 256
    int*   bbase   = bsum + 256;                  // 256
    int*   meta    = bbase + 256;                 // NE
    float* ns_srt  = (float*)(meta + NE);         // NE
    float* partial = ns_srt + NE;                 // NTILES

    (void)hipMemsetAsync(cnt, 0, 2 * NN * sizeof(int), stream);

    count_kernel<<<(NE + 255) / 256, 256, 0, stream>>>(senders, receivers, cnt, scnt);
    scan1_kernel<<<SCAN_BLKS, 256, 0, stream>>>(cnt, offs, bsum);
    scan2_kernel<<<1, 256, 0, stream>>>(bsum, bbase);
    scan3_kernel<<<SCAN_BLKS, 256, 0, stream>>>(offs, bbase, cursor);
    scatter_kernel<<<(NE + 255) / 256, 256, 0, stream>>>(senders, receivers, etypes,
                                                         scnt, cursor, meta, ns_srt);
    tile_kernel<<<NTILES, 256, 0, stream>>>(nodes, kernels, offs, meta, ns_srt,
                                            dense_w, partial);
    final_kernel<<<1, 256, 0, stream>>>(partial, dense_b, out);
}